// Round 5
// baseline (120.087 us; speedup 1.0000x reference)
//
#include <hip/hip_runtime.h>

#define NSTEPS 24
#define HALFW  2048
#define ROWS   2
#define INV2PI 0.15915494309189535f

typedef float float2v __attribute__((ext_vector_type(2)));

// Bijective swizzle (triangular XOR): verified <=2-way (free) for ALL six
// phase patterns below.
#define SWZ4(q) ((q) ^ (((q) >> 4) & 31) ^ (((q) >> 8) & 15))

// Phase maps: q (12-bit column) composition per phase. e = register elem
// (4b), L30 = t[3:0], L54 = t[5:4], W = t[7:6] (wave id). The NEXT-needed
// nibble always sits in L30 => T1/T3/T5 are wave-local (no barrier).
#define P0(e) (((e) << 8) | (L30 << 4) | (W << 2) | L54)
#define P1(e) ((L30 << 8) | ((e) << 4) | (W << 2) | L54)
#define P2(e) ((L30 << 8) | (W << 6) | (L54 << 4) | (e))
#define P3(e) (((e) << 8) | (W << 6) | (L54 << 4) | L30)
#define P4(e) ((W << 10) | (L54 << 8) | ((e) << 4) | L30)
#define P5(e) ((W << 10) | (L54 << 8) | (L30 << 4) | (e))

#define SB() __builtin_amdgcn_sched_barrier(0)

// tab[d*2048 + t*8 + p] = theta/(2*pi), laid out for the NEW phase maps.
// Same rotl12/insert-bit logic as the verified original; only q0's
// composition changed (must match P0..P5 above exactly).
__global__ void build_tab_kernel(const float* __restrict__ params,
                                 float* __restrict__ tab) {
    int idx = blockIdx.x * 256 + threadIdx.x;
    if (idx >= NSTEPS * HALFW) return;
    int d  = idx >> 11;
    int j  = idx & (HALFW - 1);
    int t  = j >> 3;
    int p  = j & 7;
    int phase = d >> 2;           // 0..5
    int k  = 3 - (d & 3);         // butterfly bit within the nibble
    int e0 = ((p >> k) << (k + 1)) | (p & ((1 << k) - 1)); // insert 0 at bit k
    int W = t >> 6, L = t & 63, L30 = L & 15, L54 = L >> 4;
    int q0;
    switch (phase) {
        case 0:  q0 = (e0 << 8) | (L30 << 4) | (W << 2) | L54; break;
        case 1:  q0 = (L30 << 8) | (e0 << 4) | (W << 2) | L54; break;
        case 2:  q0 = (L30 << 8) | (W << 6) | (L54 << 4) | e0; break;
        case 3:  q0 = (e0 << 8) | (W << 6) | (L54 << 4) | L30; break;
        case 4:  q0 = (W << 10) | (L54 << 8) | (e0 << 4) | L30; break;
        default: q0 = (W << 10) | (L54 << 8) | (L30 << 4) | e0; break;
    }
    int dd = d % 12;
    int l = ((q0 << dd) | (q0 >> (12 - dd))) & 0xFFF;       // rotl12(q0, dd)
    l &= 0x7FF;
    float theta = params[l * NSTEPS + d];   // params (2048, 24) row-major
    tab[idx] = theta * INV2PI;
}

// 8-float theta load (2x dwordx4, scalar unpack, SROA-safe).
__device__ __forceinline__ void ldth(float (&dst)[8], const float* __restrict__ p) {
    const float4* ap = (const float4*)p;
    float4 q0 = ap[0], q1 = ap[1];
    dst[0] = q0.x; dst[1] = q0.y; dst[2] = q0.z; dst[3] = q0.w;
    dst[4] = q1.x; dst[5] = q1.y; dst[6] = q1.z; dst[7] = q1.w;
}

// Packed butterfly (both rows) + hw sincos from theta (revolutions).
template<int KK>
__device__ __forceinline__ void bfly(float2v (&rp)[16], const float (&th)[8]) {
    #pragma unroll
    for (int p = 0; p < 8; ++p) {
        const int e0 = ((p >> KK) << (KK + 1)) | (p & ((1 << KK) - 1));
        const int e1 = e0 | (1 << KK);
        const float c = __builtin_amdgcn_cosf(th[p]);
        const float s = __builtin_amdgcn_sinf(th[p]);
        const float2v cv = {c, c};
        const float2v sv = {s, s};
        const float2v v0 = rp[e0], v1 = rp[e1];
        rp[e0] = __builtin_elementwise_fma(cv, v0, sv * v1);
        rp[e1] = __builtin_elementwise_fma(cv, v1, -(sv * v0));
    }
}

// 4 butterfly steps; theta double-buffer, distance-2 prefetch pinned after
// each last use (proven SB pattern).
template<int BASE>
__device__ __forceinline__ void group4(float2v (&rp)[16],
        float (&t0a)[8], float (&t1a)[8], const float* __restrict__ tb) {
    bfly<3>(rp, t0a);
    if constexpr (BASE + 2 < NSTEPS) { ldth(t0a, tb + (BASE + 2) * 2048); SB(); }
    bfly<2>(rp, t1a);
    if constexpr (BASE + 3 < NSTEPS) { ldth(t1a, tb + (BASE + 3) * 2048); SB(); }
    bfly<1>(rp, t0a);
    if constexpr (BASE + 4 < NSTEPS) { ldth(t0a, tb + (BASE + 4) * 2048); SB(); }
    bfly<0>(rp, t1a);
    if constexpr (BASE + 5 < NSTEPS) { ldth(t1a, tb + (BASE + 5) * 2048); SB(); }
}

// Transpose write/read at a phase map. Wave-local transitions (T1/T3/T5)
// use NO barrier: each wave's write-set == its own read-set (disjoint across
// waves); hw lgkmcnt orders the wave's own LDS ops. Block transitions
// (T2/T4) need exactly ONE barrier: the write-set is wave-own, so the
// trailing barrier is unnecessary (next writer of a slot == its T-reader).
#define TRW(QP) do {                                                          \
    _Pragma("unroll")                                                         \
    for (int e = 0; e < 16; ++e) {                                            \
        const int a = SWZ4(QP(e));                                            \
        lds0[a] = rp[e].x;                                                    \
        lds1[a] = rp[e].y;                                                    \
    }                                                                         \
} while (0)
#define TRR(QP) do {                                                          \
    _Pragma("unroll")                                                         \
    for (int e = 0; e < 16; ++e) {                                            \
        const int a = SWZ4(QP(e));                                            \
        rp[e].x = lds0[a];                                                    \
        rp[e].y = lds1[a];                                                    \
    }                                                                         \
} while (0)

__global__ __launch_bounds__(256, 3)
void bfly_kernel(const float* __restrict__ X,
                 const float* __restrict__ tab,
                 float* __restrict__ Y) {
    __shared__ float lds0[4096];       // 2 x 16 KiB = 32 KiB
    __shared__ float lds1[4096];
    const int t = threadIdx.x;
    const int W = t >> 6, L = t & 63, L30 = L & 15, L54 = L >> 4;
    const size_t row0 = (size_t)blockIdx.x * ROWS;

    const float* tb = tab + t * 8;
    float t0a[8], t1a[8];
    ldth(t0a, tb + 0 * 2048);
    ldth(t1a, tb + 1 * 2048);
    SB();

    float2v rp[16];
    {
        const float* xr0 = X + (row0 + 0) * 4096;
        const float* xr1 = X + (row0 + 1) * 4096;
        #pragma unroll
        for (int e = 0; e < 16; ++e) {
            const int a = P0(e);   // wave covers a dense 1 KiB block: coalesced
            rp[e].x = xr0[a];
            rp[e].y = xr1[a];
        }
    }

    group4<0 >(rp, t0a, t1a, tb);       // steps 0..3   (bits 11..8)
    TRW(P0); TRR(P1);                   // T1: wave-local, NO barrier
    group4<4 >(rp, t0a, t1a, tb);       // steps 4..7   (bits 7..4)
    TRW(P1); __syncthreads(); TRR(P2);  // T2: block, ONE barrier
    group4<8 >(rp, t0a, t1a, tb);       // steps 8..11  (bits 3..0)
    TRW(P2); TRR(P3);                   // T3: wave-local, NO barrier
    group4<12>(rp, t0a, t1a, tb);       // steps 12..15 (bits 11..8)
    TRW(P3); __syncthreads(); TRR(P4);  // T4: block, ONE barrier
    group4<16>(rp, t0a, t1a, tb);       // steps 16..19 (bits 7..4)
    TRW(P4); TRR(P5);                   // T5: wave-local, NO barrier
    group4<20>(rp, t0a, t1a, tb);       // steps 20..23 (bits 3..0)

    // P5: thread holds 16 consecutive outputs at base (W<<10)|(L54<<8)|(L30<<4)
    {
        float* yr0 = Y + (row0 + 0) * 4096;
        float* yr1 = Y + (row0 + 1) * 4096;
        const int base = (W << 10) | (L54 << 8) | (L30 << 4);
        #pragma unroll
        for (int v = 0; v < 4; ++v) {
            float4 o0, o1;
            o0.x = rp[4 * v + 0].x; o1.x = rp[4 * v + 0].y;
            o0.y = rp[4 * v + 1].x; o1.y = rp[4 * v + 1].y;
            o0.z = rp[4 * v + 2].x; o1.z = rp[4 * v + 2].y;
            o0.w = rp[4 * v + 3].x; o1.w = rp[4 * v + 3].y;
            *(float4*)&yr0[base + 4 * v] = o0;
            *(float4*)&yr1[base + 4 * v] = o1;
        }
    }
}

extern "C" void kernel_launch(void* const* d_in, const int* in_sizes, int n_in,
                              void* d_out, int out_size, void* d_ws, size_t ws_size,
                              hipStream_t stream) {
    const float* X      = (const float*)d_in[0];
    const float* params = (const float*)d_in[1];
    float* out = (float*)d_out;
    float* tab = (float*)d_ws;   // 24*2048*4 = 196,608 bytes (theta only)

    hipLaunchKernelGGL(build_tab_kernel,
                       dim3((NSTEPS * HALFW + 255) / 256), dim3(256), 0, stream,
                       params, tab);
    hipLaunchKernelGGL(bfly_kernel,
                       dim3(8192 / ROWS), dim3(256), 0, stream,
                       X, tab, out);
}

// Round 6
// 93.082 us; speedup vs baseline: 1.2901x; 1.2901x over previous
//
#include <hip/hip_runtime.h>

#define NSTEPS 24
#define HALFW  2048
#define ROWS   2
#define INV2PI 0.15915494309189535f

typedef float float2v __attribute__((ext_vector_type(2)));

// Round-1 swizzle — MEASURED 0 bank conflicts at b32 scalar (rounds 0-4).
// Reused verbatim for the float2v (8B-unit) addressing.
#define SWZ(q) ((q) ^ (((q) >> 4) & 31))
#define QA(e) (((e) << 8) | t)                              // bits 11..8 in regs
#define QB(e) ((((t) >> 4) << 8) | ((e) << 4) | ((t) & 15)) // bits 7..4  in regs
#define QC(e) (((t) << 4) | (e))                            // bits 3..0  in regs

#define SB() __builtin_amdgcn_sched_barrier(0)

// tab[d*2048 + t*8 + p] = theta/(2*pi)  (REVOLUTIONS, for v_sin/v_cos).
// Rounds 0-4 verified index mapping.
__global__ void build_tab_kernel(const float* __restrict__ params,
                                 float* __restrict__ tab) {
    int idx = blockIdx.x * 256 + threadIdx.x;
    if (idx >= NSTEPS * HALFW) return;
    int d  = idx >> 11;
    int j  = idx & (HALFW - 1);
    int t  = j >> 3;
    int p  = j & 7;
    int dd = d % 12;
    int grp = dd >> 2;            // 0: bits 11..8, 1: bits 7..4, 2: bits 3..0
    int k  = 3 - (dd & 3);        // butterfly bit within the nibble
    int e0 = ((p >> k) << (k + 1)) | (p & ((1 << k) - 1)); // insert 0 at bit k
    int q0;
    if (grp == 0)      q0 = (e0 << 8) | t;
    else if (grp == 1) q0 = ((t >> 4) << 8) | (e0 << 4) | (t & 15);
    else               q0 = (t << 4) | e0;
    int l = ((q0 << dd) | (q0 >> (12 - dd))) & 0xFFF;       // rotl12(q0, dd)
    l &= 0x7FF;
    float theta = params[l * NSTEPS + d];   // params (2048, 24) row-major
    tab[idx] = theta * INV2PI;
}

// 8-float theta load (2x dwordx4, scalar unpack, SROA-safe).
__device__ __forceinline__ void ldth(float (&dst)[8], const float* __restrict__ p) {
    const float4* ap = (const float4*)p;
    float4 q0 = ap[0], q1 = ap[1];
    dst[0] = q0.x; dst[1] = q0.y; dst[2] = q0.z; dst[3] = q0.w;
    dst[4] = q1.x; dst[5] = q1.y; dst[6] = q1.z; dst[7] = q1.w;
}

// Packed butterfly (both rows) + hw sincos from theta (revolutions).
template<int KK>
__device__ __forceinline__ void bfly(float2v (&rp)[16], const float (&th)[8]) {
    #pragma unroll
    for (int p = 0; p < 8; ++p) {
        const int e0 = ((p >> KK) << (KK + 1)) | (p & ((1 << KK) - 1));
        const int e1 = e0 | (1 << KK);
        const float c = __builtin_amdgcn_cosf(th[p]);
        const float s = __builtin_amdgcn_sinf(th[p]);
        const float2v cv = {c, c};
        const float2v sv = {s, s};
        const float2v v0 = rp[e0], v1 = rp[e1];
        rp[e0] = __builtin_elementwise_fma(cv, v0, sv * v1);
        rp[e1] = __builtin_elementwise_fma(cv, v1, -(sv * v0));
    }
}

// 4 butterfly steps; theta double-buffer, distance-2 prefetch pinned after
// each last use (proven SB pattern).
template<int BASE>
__device__ __forceinline__ void group4(float2v (&rp)[16],
        float (&t0a)[8], float (&t1a)[8], const float* __restrict__ tb) {
    bfly<3>(rp, t0a);
    if constexpr (BASE + 2 < NSTEPS) { ldth(t0a, tb + (BASE + 2) * 2048); SB(); }
    bfly<2>(rp, t1a);
    if constexpr (BASE + 3 < NSTEPS) { ldth(t1a, tb + (BASE + 3) * 2048); SB(); }
    bfly<1>(rp, t0a);
    if constexpr (BASE + 4 < NSTEPS) { ldth(t0a, tb + (BASE + 4) * 2048); SB(); }
    bfly<0>(rp, t1a);
    if constexpr (BASE + 5 < NSTEPS) { ldth(t1a, tb + (BASE + 5) * 2048); SB(); }
}

// 2-row transition at HALF the DS instruction count: the row pair {r0,r1}
// is a spectator axis of the transpose, so it vectorizes — one ds_write_b64
// + one ds_read_b64 per element instead of 2+2 b32. Addressing (in 8B
// units) is byte-for-byte the same permutation as rounds 0-4's lds0/lds1
// pair, so correctness is inherited.
#define TRANS(QS, QD) do {                                                    \
    _Pragma("unroll")                                                         \
    for (int e = 0; e < 16; ++e)                                              \
        lds[SWZ(QS(e))] = rp[e];                                              \
    __syncthreads();                                                          \
    _Pragma("unroll")                                                         \
    for (int e = 0; e < 16; ++e)                                              \
        rp[e] = lds[SWZ(QD(e))];                                              \
    __syncthreads();                                                          \
} while (0)

// Pool model (fit to rounds 0-4): waves/SIMD = floor(256 / VGPR).
__global__ __launch_bounds__(256, 3)
void bfly_kernel(const float* __restrict__ X,
                 const float* __restrict__ tab,
                 float* __restrict__ Y) {
    __shared__ float2v lds[4096];      // 32 KiB, rows interleaved
    const int t = threadIdx.x;
    const size_t row0 = (size_t)blockIdx.x * ROWS;

    const float* tb = tab + t * 8;
    float t0a[8], t1a[8];
    ldth(t0a, tb + 0 * 2048);
    ldth(t1a, tb + 1 * 2048);
    SB();

    float2v rp[16];
    {
        const float* xr0 = X + (row0 + 0) * 4096;
        const float* xr1 = X + (row0 + 1) * 4096;
        #pragma unroll
        for (int e = 0; e < 16; ++e) {
            rp[e].x = xr0[QA(e)];  // coalesced: consecutive lanes, consecutive addr
            rp[e].y = xr1[QA(e)];
        }
    }

    group4<0 >(rp, t0a, t1a, tb);   // steps 0..3   (bits 11..8)
    TRANS(QA, QB);
    group4<4 >(rp, t0a, t1a, tb);   // steps 4..7   (bits 7..4)
    TRANS(QB, QC);
    group4<8 >(rp, t0a, t1a, tb);   // steps 8..11  (bits 3..0)
    TRANS(QC, QA);
    group4<12>(rp, t0a, t1a, tb);   // steps 12..15 (bits 11..8)
    TRANS(QA, QB);
    group4<16>(rp, t0a, t1a, tb);   // steps 16..19 (bits 7..4)
    TRANS(QB, QC);
    group4<20>(rp, t0a, t1a, tb);   // steps 20..23 (bits 3..0)

    // grouping C: thread t holds 16 consecutive outputs per row -> float4 stores
    {
        float* yr0 = Y + (row0 + 0) * 4096;
        float* yr1 = Y + (row0 + 1) * 4096;
        #pragma unroll
        for (int v = 0; v < 4; ++v) {
            float4 o0, o1;
            o0.x = rp[4 * v + 0].x; o1.x = rp[4 * v + 0].y;
            o0.y = rp[4 * v + 1].x; o1.y = rp[4 * v + 1].y;
            o0.z = rp[4 * v + 2].x; o1.z = rp[4 * v + 2].y;
            o0.w = rp[4 * v + 3].x; o1.w = rp[4 * v + 3].y;
            *(float4*)&yr0[t * 16 + 4 * v] = o0;
            *(float4*)&yr1[t * 16 + 4 * v] = o1;
        }
    }
}

extern "C" void kernel_launch(void* const* d_in, const int* in_sizes, int n_in,
                              void* d_out, int out_size, void* d_ws, size_t ws_size,
                              hipStream_t stream) {
    const float* X      = (const float*)d_in[0];
    const float* params = (const float*)d_in[1];
    float* out = (float*)d_out;
    float* tab = (float*)d_ws;   // 24*2048*4 = 196,608 bytes (theta only)

    hipLaunchKernelGGL(build_tab_kernel,
                       dim3((NSTEPS * HALFW + 255) / 256), dim3(256), 0, stream,
                       params, tab);
    hipLaunchKernelGGL(bfly_kernel,
                       dim3(8192 / ROWS), dim3(256), 0, stream,
                       X, tab, out);
}